// Round 1
// 274.628 us; speedup vs baseline: 1.0174x; 1.0174x over previous
//
#include <hip/hip_runtime.h>
#include <math.h>

#define N_NODES 100000
#define N_EDGES 1600000
#define C_DIM 40
#define NGROUPS 6250                      // 100000 / 16 exactly

#define BSZ 256                           // nodes per bucket
#define NB  ((N_NODES + BSZ - 1) / BSZ)   // 391
#define EB  4096                          // edges per hist/scatter block
#define NBE ((N_EDGES + EB - 1) / EB)     // 391

// ---------------- workspace layout (4-byte units) ----------------
#define OFF_DINV 0                        // float[100000]
#define OFF_BB   100000                   // int[NB+1]
#define OFF_CS   100392                   // int[NB] column sums
#define OFF_ROW  100800                   // int[N+1]
#define OFF_H    200802                   // int[NBE*NB]
#define OFF_REC2 353684                   // int2[E] sorted records (even -> 8B aligned)
#define OFF_H1P  3553684                  // ushort[N*64] bf16 h1'; unsorted rec aliases here
#define OFF_H2P  6753684                  // ushort[N*64] bf16 h2' (128B padded rows)
#define OFF_AGG1 9953684                  // float[N*64]

typedef float floatx4 __attribute__((ext_vector_type(4)));
typedef short shortx8 __attribute__((ext_vector_type(8)));

__device__ inline unsigned short f2bf(float f) {
    unsigned int u = __float_as_uint(f);
    u += 0x7FFF + ((u >> 16) & 1);        // round to nearest even
    return (unsigned short)(u >> 16);
}
__device__ inline float bf2f(unsigned short h) {
    return __uint_as_float(((unsigned int)h) << 16);
}
__device__ inline float bflo(unsigned int u) { return __uint_as_float(u << 16); }
__device__ inline float bfhi(unsigned int u) { return __uint_as_float(u & 0xFFFF0000u); }

// ---------- per-block bucket histogram: H[b][j] + global column sums ----------
__global__ __launch_bounds__(512) void k_hist2d(const int* __restrict__ ei,
                                                int* __restrict__ H,
                                                int* __restrict__ colsum) {
    __shared__ int bins[NB];
    int t = threadIdx.x, b = blockIdx.x;
    for (int i = t; i < NB; i += 512) bins[i] = 0;
    __syncthreads();
    int base = b * EB;
    for (int i = t; i < EB; i += 512) {
        int e = base + i;
        if (e < N_EDGES) atomicAdd(&bins[ei[N_EDGES + e] >> 8], 1);
    }
    __syncthreads();
    for (int i = t; i < NB; i += 512) {
        int c = bins[i];
        H[b * NB + i] = c;
        if (c) atomicAdd(&colsum[i], c);
    }
}

// ---------- column scan (self-computes bucketBase[j] from colsum) ----------
__global__ __launch_bounds__(512) void k_colscan(int* __restrict__ H,
                                                 const int* __restrict__ colsum,
                                                 int* __restrict__ bucketBase,
                                                 int* __restrict__ rowStart) {
    __shared__ int sd[512];
    __shared__ int sbase;
    int t = threadIdx.x, j = blockIdx.x;
    int p = 0;
    for (int i = t; i < j; i += 512) p += colsum[i];
    sd[t] = p;
    __syncthreads();
    for (int off = 256; off > 0; off >>= 1) {
        if (t < off) sd[t] += sd[t + off];
        __syncthreads();
    }
    if (t == 0) sbase = sd[0];
    __syncthreads();
    int base = sbase;
    if (t == 0) {
        bucketBase[j] = base;
        if (j == NB - 1) { bucketBase[NB] = base + colsum[j]; rowStart[N_NODES] = N_EDGES; }
    }
    __syncthreads();
    int val = (t < NBE) ? H[t * NB + j] : 0;
    sd[t] = val;
    __syncthreads();
    for (int off = 1; off < 512; off <<= 1) {
        int v = (t >= off) ? sd[t - off] : 0;
        __syncthreads();
        sd[t] += v;
        __syncthreads();
    }
    if (t < NBE) H[t * NB + j] = base + sd[t] - val;
}

// ---------- scatter into bucket regions (LDS cursors, no global atomics) ----------
__global__ __launch_bounds__(512) void k_scatter(const int* __restrict__ ei,
                                                 const float* __restrict__ w,
                                                 const int* __restrict__ blockBase,
                                                 int2* __restrict__ rec) {
    __shared__ int bases[NB];
    __shared__ int cur[NB];
    int t = threadIdx.x, b = blockIdx.x;
    for (int i = t; i < NB; i += 512) { bases[i] = blockBase[b * NB + i]; cur[i] = 0; }
    __syncthreads();
    int base = b * EB;
    for (int i = t; i < EB; i += 512) {
        int e = base + i;
        if (e < N_EDGES) {
            int s = ei[e], d = ei[N_EDGES + e];
            float wv = w[e];
            int bin = d >> 8;
            int pos = bases[bin] + atomicAdd(&cur[bin], 1);
            rec[pos] = make_int2(s | ((d & 255) << 17), __float_as_int(wv));
        }
    }
}

// ---------- per-bucket counting sort; payload = w*dinv[dst]; x = src byte-offset ----------
__global__ __launch_bounds__(512) void k_bsort(const int* __restrict__ bucketBase,
                                               const int2* __restrict__ rec,
                                               int2* __restrict__ rec2,
                                               float* __restrict__ dinv,
                                               int* __restrict__ rowStart) {
    __shared__ int   cnt[256];
    __shared__ float wsum[256];
    __shared__ int   cur[256];
    __shared__ int   sd[512];
    int t = threadIdx.x, b = blockIdx.x;
    if (t < 256) { cnt[t] = 0; wsum[t] = 0.f; }
    __syncthreads();
    int r0 = bucketBase[b], r1 = bucketBase[b + 1];
    for (int i = r0 + t; i < r1; i += 512) {
        int2 rv = rec[i];
        int l = (rv.x >> 17) & 255;
        atomicAdd(&cnt[l], 1);
        atomicAdd(&wsum[l], __int_as_float(rv.y));
    }
    __syncthreads();
    int val = (t < 256) ? cnt[t] : 0;
    sd[t] = val;
    __syncthreads();
    for (int off = 1; off < 512; off <<= 1) {
        int v = (t >= off) ? sd[t - off] : 0;
        __syncthreads();
        sd[t] += v;
        __syncthreads();
    }
    float dloc = 0.f;
    if (t < 256) {
        int excl = sd[t] - val;
        cur[t] = excl;
        int node = b * BSZ + t;
        dloc = rsqrtf(1.f + wsum[t]);
        if (node < N_NODES) {
            rowStart[node] = r0 + excl;
            dinv[node] = dloc;
        }
    }
    __syncthreads();
    if (t < 256) wsum[t] = dloc;
    __syncthreads();
    for (int i = r0 + t; i < r1; i += 512) {
        int2 rv = rec[i];
        int l = (rv.x >> 17) & 255;
        float cpart = __int_as_float(rv.y) * wsum[l];   // w * dinv[dst]
        int pos = r0 + atomicAdd(&cur[l], 1);
        rec2[pos] = make_int2((rv.x & 0x1FFFF) << 7, __float_as_int(cpart));  // src*128B
    }
}

// ---------- h1' = (x @ W1) * dinv[row] via MFMA, stored bf16 ----------
__global__ __launch_bounds__(256) void k_mm1(const float* __restrict__ x,
                                             const float* __restrict__ W1,
                                             const float* __restrict__ dinv,
                                             unsigned short* __restrict__ h1p) {
    int t = threadIdx.x, lane = t & 63, wv = t >> 6;
    int m = lane & 15, quad = lane >> 4;
    int wid = blockIdx.x * 4 + wv, nw = gridDim.x * 4;
    shortx8 B[2][4];
#pragma unroll
    for (int kc = 0; kc < 2; ++kc)
#pragma unroll
        for (int tt = 0; tt < 4; ++tt)
#pragma unroll
            for (int j = 0; j < 8; ++j) {
                int k = kc * 32 + quad * 8 + j;
                B[kc][tt][j] = (short)f2bf(W1[k * 64 + tt * 16 + m]);
            }
    for (int g = wid; g < NGROUPS; g += nw) {
        int n0 = g * 16;
        const float* xr = x + (long)(n0 + m) * 64 + quad * 8;
        floatx4 xa = ((const floatx4*)xr)[0];
        floatx4 xb = ((const floatx4*)(xr + 4))[0];
        floatx4 xc = ((const floatx4*)(xr + 32))[0];
        floatx4 xd = ((const floatx4*)(xr + 36))[0];
        shortx8 A0, A1;
#pragma unroll
        for (int j = 0; j < 4; ++j) {
            A0[j] = (short)f2bf(xa[j]);
            A0[4 + j] = (short)f2bf(xb[j]);
            A1[j] = (short)f2bf(xc[j]);
            A1[4 + j] = (short)f2bf(xd[j]);
        }
        floatx4 acc[4];
#pragma unroll
        for (int tt = 0; tt < 4; ++tt) {
            acc[tt] = (floatx4){0.f, 0.f, 0.f, 0.f};
            acc[tt] = __builtin_amdgcn_mfma_f32_16x16x32_bf16(A0, B[0][tt], acc[tt], 0, 0, 0);
            acc[tt] = __builtin_amdgcn_mfma_f32_16x16x32_bf16(A1, B[1][tt], acc[tt], 0, 0, 0);
        }
        floatx4 dv = ((const floatx4*)(dinv + n0 + quad * 4))[0];
#pragma unroll
        for (int reg = 0; reg < 4; ++reg) {
            int node = n0 + quad * 4 + reg;
            float d = dv[reg];
#pragma unroll
            for (int tt = 0; tt < 4; ++tt)
                h1p[(long)node * 64 + tt * 16 + m] = f2bf(acc[tt][reg] * d);
        }
    }
}

// ---------- agg1: 4 edge-slots x 16 lanes, 20-edge predicated unroll ----------
// 5 independent 8B gather loads per lane in flight per iteration (was 2).
__global__ __launch_bounds__(256) void k_agg1(const int* __restrict__ rowStart,
                                              const int2* __restrict__ rec2,
                                              const float* __restrict__ dinv,
                                              const unsigned short* __restrict__ h1p,
                                              float* __restrict__ agg1) {
    __shared__ int2 cache[4][64];
    int t = threadIdx.x, lane = t & 63, wv = t >> 6;
    int node = blockIdx.x * 4 + wv;
    if (node >= N_NODES) return;
    int2* wc = cache[wv];
    wc[lane] = make_int2(0, 0);
    const char* hb = (const char*)h1p;
    int eslot = lane >> 4;
    int c = lane & 15;
    int lo = c << 3;
    float dn = dinv[node];
    float a0 = 0.f, a1 = 0.f, a2 = 0.f, a3 = 0.f;
    float b0 = 0.f, b1 = 0.f, b2v = 0.f, b3 = 0.f;
    if (eslot == 0) {
        const unsigned int* sp = (const unsigned int*)(hb + ((long)node << 7) + lo);
        unsigned int u0 = sp[0], u1 = sp[1];
        a0 = bflo(u0) * dn; a1 = bfhi(u0) * dn;
        a2 = bflo(u1) * dn; a3 = bfhi(u1) * dn;
    }
    int s0 = rowStart[node], s1 = rowStart[node + 1];
    for (int base = s0; base < s1; base += 64) {
        int idx = base + lane;
        if (idx < s1) wc[lane] = rec2[idx];
        __builtin_amdgcn_wave_barrier();
        int cnt = min(64, s1 - base);
        for (int j = 0; j < cnt; j += 20) {
            int2 e0, e1, e2, e3, e4;
            float w0, w1, w2, w3, w4;
            { int jj = j + eslot;      bool v = jj < cnt; e0 = wc[v ? jj : j]; w0 = v ? __int_as_float(e0.y) : 0.f; }
            { int jj = j + 4 + eslot;  bool v = jj < cnt; e1 = wc[v ? jj : j]; w1 = v ? __int_as_float(e1.y) : 0.f; }
            { int jj = j + 8 + eslot;  bool v = jj < cnt; e2 = wc[v ? jj : j]; w2 = v ? __int_as_float(e2.y) : 0.f; }
            { int jj = j + 12 + eslot; bool v = jj < cnt; e3 = wc[v ? jj : j]; w3 = v ? __int_as_float(e3.y) : 0.f; }
            { int jj = j + 16 + eslot; bool v = jj < cnt; e4 = wc[v ? jj : j]; w4 = v ? __int_as_float(e4.y) : 0.f; }
            uint2 q0 = *(const uint2*)(hb + e0.x + lo);
            uint2 q1 = *(const uint2*)(hb + e1.x + lo);
            uint2 q2 = *(const uint2*)(hb + e2.x + lo);
            uint2 q3 = *(const uint2*)(hb + e3.x + lo);
            uint2 q4 = *(const uint2*)(hb + e4.x + lo);
            a0 = fmaf(bflo(q0.x), w0, a0); a1 = fmaf(bfhi(q0.x), w0, a1);
            a2 = fmaf(bflo(q0.y), w0, a2); a3 = fmaf(bfhi(q0.y), w0, a3);
            b0 = fmaf(bflo(q1.x), w1, b0); b1 = fmaf(bfhi(q1.x), w1, b1);
            b2v = fmaf(bflo(q1.y), w1, b2v); b3 = fmaf(bfhi(q1.y), w1, b3);
            a0 = fmaf(bflo(q2.x), w2, a0); a1 = fmaf(bfhi(q2.x), w2, a1);
            a2 = fmaf(bflo(q2.y), w2, a2); a3 = fmaf(bfhi(q2.y), w2, a3);
            b0 = fmaf(bflo(q3.x), w3, b0); b1 = fmaf(bfhi(q3.x), w3, b1);
            b2v = fmaf(bflo(q3.y), w3, b2v); b3 = fmaf(bfhi(q3.y), w3, b3);
            a0 = fmaf(bflo(q4.x), w4, a0); a1 = fmaf(bfhi(q4.x), w4, a1);
            a2 = fmaf(bflo(q4.y), w4, a2); a3 = fmaf(bfhi(q4.y), w4, a3);
        }
        __builtin_amdgcn_wave_barrier();
    }
    a0 += b0; a1 += b1; a2 += b2v; a3 += b3;
    a0 += __shfl_xor(a0, 16, 64); a0 += __shfl_xor(a0, 32, 64);
    a1 += __shfl_xor(a1, 16, 64); a1 += __shfl_xor(a1, 32, 64);
    a2 += __shfl_xor(a2, 16, 64); a2 += __shfl_xor(a2, 32, 64);
    a3 += __shfl_xor(a3, 16, 64); a3 += __shfl_xor(a3, 32, 64);
    if (eslot == 0) {
        *(float4*)(agg1 + ((long)node << 6) + (c << 2)) = make_float4(a0, a1, a2, a3);
    }
}

// ---------- h2' = (relu(agg1+b1) @ W2) * dinv via MFMA, bf16, 128B-padded rows ----------
__global__ __launch_bounds__(256) void k_mm2(const float* __restrict__ agg1,
                                             const float* __restrict__ b1,
                                             const float* __restrict__ W2,
                                             const float* __restrict__ dinv,
                                             unsigned short* __restrict__ h2p) {
    int t = threadIdx.x, lane = t & 63, wv = t >> 6;
    int m = lane & 15, quad = lane >> 4;
    int wid = blockIdx.x * 4 + wv, nw = gridDim.x * 4;
    shortx8 B[2][3];
#pragma unroll
    for (int kc = 0; kc < 2; ++kc)
#pragma unroll
        for (int tt = 0; tt < 3; ++tt) {
            int n = tt * 16 + m;
#pragma unroll
            for (int j = 0; j < 8; ++j) {
                int k = kc * 32 + quad * 8 + j;
                B[kc][tt][j] = (n < C_DIM) ? (short)f2bf(W2[k * C_DIM + n]) : (short)0;
            }
        }
    floatx4 ba0 = ((const floatx4*)(b1 + quad * 8))[0];
    floatx4 ba1 = ((const floatx4*)(b1 + quad * 8 + 4))[0];
    floatx4 bb0 = ((const floatx4*)(b1 + 32 + quad * 8))[0];
    floatx4 bb1 = ((const floatx4*)(b1 + 32 + quad * 8 + 4))[0];
    for (int g = wid; g < NGROUPS; g += nw) {
        int n0 = g * 16;
        const float* xr = agg1 + (long)(n0 + m) * 64 + quad * 8;
        floatx4 xa = ((const floatx4*)xr)[0];
        floatx4 xb = ((const floatx4*)(xr + 4))[0];
        floatx4 xc = ((const floatx4*)(xr + 32))[0];
        floatx4 xd = ((const floatx4*)(xr + 36))[0];
        shortx8 A0, A1;
#pragma unroll
        for (int j = 0; j < 4; ++j) {
            A0[j]     = (short)f2bf(fmaxf(xa[j] + ba0[j], 0.f));
            A0[4 + j] = (short)f2bf(fmaxf(xb[j] + ba1[j], 0.f));
            A1[j]     = (short)f2bf(fmaxf(xc[j] + bb0[j], 0.f));
            A1[4 + j] = (short)f2bf(fmaxf(xd[j] + bb1[j], 0.f));
        }
        floatx4 acc[3];
#pragma unroll
        for (int tt = 0; tt < 3; ++tt) {
            acc[tt] = (floatx4){0.f, 0.f, 0.f, 0.f};
            acc[tt] = __builtin_amdgcn_mfma_f32_16x16x32_bf16(A0, B[0][tt], acc[tt], 0, 0, 0);
            acc[tt] = __builtin_amdgcn_mfma_f32_16x16x32_bf16(A1, B[1][tt], acc[tt], 0, 0, 0);
        }
        floatx4 dv = ((const floatx4*)(dinv + n0 + quad * 4))[0];
#pragma unroll
        for (int reg = 0; reg < 4; ++reg) {
            int node = n0 + quad * 4 + reg;
            float d = dv[reg];
#pragma unroll
            for (int tt = 0; tt < 3; ++tt) {
                int col = tt * 16 + m;
                if (col < C_DIM)
                    h2p[(long)node * 64 + col] = f2bf(acc[tt][reg] * d);
            }
        }
    }
}

// ---------- agg2: 3 edge-slots x 20 lanes, 21-edge predicated unroll + softmax ----------
// 7 independent 4B gather loads per lane in flight per iteration (was 2).
__global__ __launch_bounds__(256) void k_agg2(const int* __restrict__ rowStart,
                                              const int2* __restrict__ rec2,
                                              const float* __restrict__ dinv,
                                              const unsigned short* __restrict__ h2p,
                                              const float* __restrict__ b2,
                                              float* __restrict__ out) {
    __shared__ int2 cache[4][64];
    int t = threadIdx.x, lane = t & 63, wv = t >> 6;
    int node = blockIdx.x * 4 + wv;
    if (node >= N_NODES) return;
    int2* wc = cache[wv];
    wc[lane] = make_int2(0, 0);
    const char* hb = (const char*)h2p;
    int eslot = lane / 20;
    int c = lane - eslot * 20;
    bool elane = eslot < 3;
    int lo = c << 2;
    float dn = dinv[node];
    float alo0 = 0.f, ahi0 = 0.f, alo1 = 0.f, ahi1 = 0.f;
    if (eslot == 0) {
        unsigned int u = *(const unsigned int*)(hb + ((long)node << 7) + lo);
        alo0 = bflo(u) * dn;
        ahi0 = bfhi(u) * dn;
    }
    int s0 = rowStart[node], s1 = rowStart[node + 1];
    for (int base = s0; base < s1; base += 64) {
        int idx = base + lane;
        if (idx < s1) wc[lane] = rec2[idx];
        __builtin_amdgcn_wave_barrier();
        int cnt = min(64, s1 - base);
        for (int j = 0; j < cnt; j += 21) {
            int2 e0, e1, e2, e3, e4, e5, e6;
            float f0, f1, f2, f3, f4, f5, f6;
            { int jj = j + eslot;      bool v = elane && jj < cnt; e0 = wc[v ? jj : j]; f0 = v ? __int_as_float(e0.y) : 0.f; }
            { int jj = j + 3 + eslot;  bool v = elane && jj < cnt; e1 = wc[v ? jj : j]; f1 = v ? __int_as_float(e1.y) : 0.f; }
            { int jj = j + 6 + eslot;  bool v = elane && jj < cnt; e2 = wc[v ? jj : j]; f2 = v ? __int_as_float(e2.y) : 0.f; }
            { int jj = j + 9 + eslot;  bool v = elane && jj < cnt; e3 = wc[v ? jj : j]; f3 = v ? __int_as_float(e3.y) : 0.f; }
            { int jj = j + 12 + eslot; bool v = elane && jj < cnt; e4 = wc[v ? jj : j]; f4 = v ? __int_as_float(e4.y) : 0.f; }
            { int jj = j + 15 + eslot; bool v = elane && jj < cnt; e5 = wc[v ? jj : j]; f5 = v ? __int_as_float(e5.y) : 0.f; }
            { int jj = j + 18 + eslot; bool v = elane && jj < cnt; e6 = wc[v ? jj : j]; f6 = v ? __int_as_float(e6.y) : 0.f; }
            unsigned int q0 = *(const unsigned int*)(hb + e0.x + lo);
            unsigned int q1 = *(const unsigned int*)(hb + e1.x + lo);
            unsigned int q2 = *(const unsigned int*)(hb + e2.x + lo);
            unsigned int q3 = *(const unsigned int*)(hb + e3.x + lo);
            unsigned int q4 = *(const unsigned int*)(hb + e4.x + lo);
            unsigned int q5 = *(const unsigned int*)(hb + e5.x + lo);
            unsigned int q6 = *(const unsigned int*)(hb + e6.x + lo);
            alo0 = fmaf(bflo(q0), f0, alo0); ahi0 = fmaf(bfhi(q0), f0, ahi0);
            alo1 = fmaf(bflo(q1), f1, alo1); ahi1 = fmaf(bfhi(q1), f1, ahi1);
            alo0 = fmaf(bflo(q2), f2, alo0); ahi0 = fmaf(bfhi(q2), f2, ahi0);
            alo1 = fmaf(bflo(q3), f3, alo1); ahi1 = fmaf(bfhi(q3), f3, ahi1);
            alo0 = fmaf(bflo(q4), f4, alo0); ahi0 = fmaf(bfhi(q4), f4, ahi0);
            alo1 = fmaf(bflo(q5), f5, alo1); ahi1 = fmaf(bfhi(q5), f5, ahi1);
            alo0 = fmaf(bflo(q6), f6, alo0); ahi0 = fmaf(bfhi(q6), f6, ahi0);
        }
        __builtin_amdgcn_wave_barrier();
    }
    float alo = alo0 + alo1, ahi = ahi0 + ahi1;
    float t1 = __shfl(alo, lane + 20, 64), t2 = __shfl(alo, lane + 40, 64);
    float t3 = __shfl(ahi, lane + 20, 64), t4 = __shfl(ahi, lane + 40, 64);
    alo = alo + t1 + t2;
    ahi = ahi + t3 + t4;
    bool act = lane < 20;
    float2 bb = ((const float2*)b2)[c];
    float vlo = act ? alo + bb.x : -INFINITY;
    float vhi = act ? ahi + bb.y : -INFINITY;
    // active lanes all live in 0..19 (subset of the low 32-lane group):
    // 5-level butterfly over offsets 16..1 suffices.
    float m = fmaxf(vlo, vhi);
#pragma unroll
    for (int off = 16; off; off >>= 1) m = fmaxf(m, __shfl_xor(m, off, 64));
    const float LOG2E = 1.4426950408889634f;
    const float LN2   = 0.6931471805599453f;
    float exlo = act ? __builtin_amdgcn_exp2f((vlo - m) * LOG2E) : 0.f;
    float exhi = act ? __builtin_amdgcn_exp2f((vhi - m) * LOG2E) : 0.f;
    float s = exlo + exhi;
#pragma unroll
    for (int off = 16; off; off >>= 1) s += __shfl_xor(s, off, 64);
    float ls = m + __builtin_amdgcn_logf(s) * LN2;   // v_log_f32 = log2
    if (act) {
        *(float2*)(out + (long)node * C_DIM + (c << 1)) = make_float2(vlo - ls, vhi - ls);
    }
}

extern "C" void kernel_launch(void* const* d_in, const int* in_sizes, int n_in,
                              void* d_out, int out_size, void* d_ws, size_t ws_size,
                              hipStream_t stream) {
    const float* x  = (const float*)d_in[0];
    const int*   ei = (const int*)d_in[1];
    const float* w  = (const float*)d_in[2];
    const float* W1 = (const float*)d_in[3];
    const float* b1 = (const float*)d_in[4];
    const float* W2 = (const float*)d_in[5];
    const float* b2 = (const float*)d_in[6];
    float* out = (float*)d_out;

    float* wsf = (float*)d_ws;
    int*   wsi = (int*)d_ws;
    float* dinv       = wsf + OFF_DINV;
    int*   bucketBase = wsi + OFF_BB;
    int*   colsum     = wsi + OFF_CS;
    int*   rowStart   = wsi + OFF_ROW;
    int*   H          = wsi + OFF_H;
    int2*  rec2       = (int2*)(wsi + OFF_REC2);
    int2*  rec        = (int2*)(wsi + OFF_H1P);              // dead before h1p written
    unsigned short* h1p = (unsigned short*)(wsi + OFF_H1P);
    unsigned short* h2p = (unsigned short*)(wsi + OFF_H2P);
    float* agg1       = wsf + OFF_AGG1;

    // CSR build — zero global atomics except 391-bin colsum
    hipMemsetAsync(colsum, 0, NB * sizeof(int), stream);
    k_hist2d<<<NBE, 512, 0, stream>>>(ei, H, colsum);
    k_colscan<<<NB, 512, 0, stream>>>(H, colsum, bucketBase, rowStart);
    k_scatter<<<NBE, 512, 0, stream>>>(ei, w, H, rec);
    k_bsort<<<NB, 512, 0, stream>>>(bucketBase, rec, rec2, dinv, rowStart);

    // layer 1 (MFMA matmul)
    k_mm1<<<512, 256, 0, stream>>>(x, W1, dinv, h1p);
    k_agg1<<<(N_NODES + 3) / 4, 256, 0, stream>>>(rowStart, rec2, dinv, h1p, agg1);

    // layer 2 (MFMA matmul + fused bias/log-softmax epilogue)
    k_mm2<<<512, 256, 0, stream>>>(agg1, b1, W2, dinv, h2p);
    k_agg2<<<(N_NODES + 3) / 4, 256, 0, stream>>>(rowStart, rec2, dinv, h2p, b2, out);
}